// Round 1
// 235.564 us; speedup vs baseline: 1.1769x; 1.1769x over previous
//
#include <hip/hip_runtime.h>
#include <hip/hip_bf16.h>

typedef __bf16 bf16;
typedef __bf16 bf16x8 __attribute__((ext_vector_type(8)));
typedef float  f32x4  __attribute__((ext_vector_type(4)));

#define MFMA16(a,b,c) __builtin_amdgcn_mfma_f32_16x16x32_bf16((a),(b),(c),0,0,0)

static const int BATCH = 8;
static const int SEQ   = 2048;
static const int HID   = 512;
static const int MTOT  = BATCH * SEQ;  // 16384

// async 16B global->LDS. LDS dest must be WAVE-UNIFORM; HW adds lane*16.
__device__ __forceinline__ void gl2lds16(const void* g, void* l) {
    __builtin_amdgcn_global_load_lds(
        (const __attribute__((address_space(1))) void*)g,
        (__attribute__((address_space(3))) void*)l, 16, 0, 0);
}

// ---------------------------------------------------------------------------
// kernel 1: convert x fp32 -> bf16 (once; k_qkv z-blocks then read bf16)
// ---------------------------------------------------------------------------
__global__ void k_convert_x(const float* __restrict__ x, bf16* __restrict__ xb, int n4) {
    int i = blockIdx.x * blockDim.x + threadIdx.x;
    int stride = gridDim.x * blockDim.x;
    for (; i < n4; i += stride) {
        float4 v = ((const float4*)x)[i];
        union { bf16 h[4]; uint2 u; } o;
        o.h[0] = (bf16)v.x; o.h[1] = (bf16)v.y; o.h[2] = (bf16)v.z; o.h[3] = (bf16)v.w;
        ((uint2*)xb)[i] = o.u;
    }
}

// ---------------------------------------------------------------------------
// kernel 2: transpose W[512][512] fp32 -> WT[512][512] bf16  (z = q/k/v)
// ---------------------------------------------------------------------------
__global__ void k_transpose_w(const float* __restrict__ Wq, const float* __restrict__ Wk,
                              const float* __restrict__ Wv, bf16* __restrict__ wt) {
    int z = blockIdx.z;
    const float* W = (z == 0) ? Wq : (z == 1) ? Wk : Wv;
    bf16* WT = wt + (size_t)z * HID * HID;
    __shared__ float tile[32][33];
    int t  = threadIdx.x;
    int tx = t & 31, ty = t >> 5;
    int f0 = blockIdx.y * 32, h0 = blockIdx.x * 32;
    for (int i = 0; i < 32; i += 8)
        tile[ty + i][tx] = W[(size_t)(f0 + ty + i) * HID + h0 + tx];
    __syncthreads();
    for (int i = 0; i < 32; i += 8)
        WT[(size_t)(h0 + ty + i) * HID + f0 + tx] = (bf16)tile[tx][ty + i];
}

// ---------------------------------------------------------------------------
// kernel 3: QKV GEMM, m97-style: async DMA dbuf staging (BK=64, XOR-swizzled
// LDS, 1 barrier/buffer). z=2 (V) fuses the transpose: acc -> LDS transpose
// (reusing dbuf space) -> coalesced stores to vt[b][h][s]. No vb buffer.
// ---------------------------------------------------------------------------
__global__ __launch_bounds__(256) void
k_qkv(const bf16* __restrict__ xb, const bf16* __restrict__ wt,
      const float* __restrict__ bq, const float* __restrict__ bk, const float* __restrict__ bv,
      bf16* __restrict__ qb, bf16* __restrict__ kb, bf16* __restrict__ vt) {
    __shared__ __align__(16) char sm[65536];   // A/B dbuf; reused for V transpose
    int z = blockIdx.z;
    const bf16*  WT   = wt + (size_t)z * HID * HID;
    const float* bias = (z == 0) ? bq : (z == 1) ? bk : bv;
    float scale = (z == 0) ? 0.044194173824159216f : 1.0f;

    int m0 = blockIdx.y * 128, n0 = blockIdx.x * 128;
    int t = threadIdx.x;
    int w = t >> 6, lane = t & 63, quad = lane >> 4, l15 = lane & 15;
    int wr = w >> 1, wc = w & 1;

    // ---- DMA lane pointers: chunk p = i*256 + t; row = p>>3, ch = p&7 swizzled
    int rowA = t >> 3;
    int chS  = (t & 7) ^ (rowA & 7);
    const char* xga = (const char*)xb + ((size_t)(m0 + rowA) * 512 + chS * 8) * 2;
    const char* wga = (const char*)WT + ((size_t)(n0 + rowA) * 512 + chS * 8) * 2;

    // ---- LDS frag base addresses (A at 0, B at 16384; row stride 128 B)
    const char* aK0 = sm + (wr * 64 + l15) * 128 + ((quad ^ (l15 & 7)) * 16);
    const char* aK1 = sm + (wr * 64 + l15) * 128 + (((4 + quad) ^ (l15 & 7)) * 16);
    const char* bK0 = sm + 16384 + (wc * 64 + l15) * 128 + ((quad ^ (l15 & 7)) * 16);
    const char* bK1 = sm + 16384 + (wc * 64 + l15) * 128 + (((4 + quad) ^ (l15 & 7)) * 16);

    f32x4 acc[4][4] = {};

#define QSTAGE(S)                                                             \
    {                                                                         \
        _Pragma("unroll")                                                     \
        for (int i = 0; i < 4; i++)                                           \
            gl2lds16(xga + i * 32768, sm + (S) * 32768 + i * 4096 + w * 1024);\
        _Pragma("unroll")                                                     \
        for (int i = 0; i < 4; i++)                                           \
            gl2lds16(wga + i * 32768,                                         \
                     sm + (S) * 32768 + 16384 + i * 4096 + w * 1024);         \
        xga += 128; wga += 128;                                               \
    }

#define QCOMP(CUR)                                                            \
    {                                                                         \
        bf16x8 af[4], bfr[4];                                                 \
        _Pragma("unroll")                                                     \
        for (int mt = 0; mt < 4; mt++)                                        \
            af[mt] = *(const bf16x8*)(aK0 + mt * 2048 + (CUR) * 32768);       \
        _Pragma("unroll")                                                     \
        for (int nt = 0; nt < 4; nt++)                                        \
            bfr[nt] = *(const bf16x8*)(bK0 + nt * 2048 + (CUR) * 32768);      \
        _Pragma("unroll")                                                     \
        for (int mt = 0; mt < 4; mt++)                                        \
            _Pragma("unroll")                                                 \
            for (int nt = 0; nt < 4; nt++)                                    \
                acc[mt][nt] = MFMA16(af[mt], bfr[nt], acc[mt][nt]);           \
        _Pragma("unroll")                                                     \
        for (int mt = 0; mt < 4; mt++)                                        \
            af[mt] = *(const bf16x8*)(aK1 + mt * 2048 + (CUR) * 32768);       \
        _Pragma("unroll")                                                     \
        for (int nt = 0; nt < 4; nt++)                                        \
            bfr[nt] = *(const bf16x8*)(bK1 + nt * 2048 + (CUR) * 32768);      \
        _Pragma("unroll")                                                     \
        for (int mt = 0; mt < 4; mt++)                                        \
            _Pragma("unroll")                                                 \
            for (int nt = 0; nt < 4; nt++)                                    \
                acc[mt][nt] = MFMA16(af[mt], bfr[nt], acc[mt][nt]);           \
    }

    QSTAGE(0);
    __syncthreads();
    for (int ii = 0; ii < 4; ii++) {
        QSTAGE(1);
        QCOMP(0);
        __syncthreads();
        if (ii < 3) QSTAGE(0);
        QCOMP(1);
        __syncthreads();
    }
#undef QSTAGE
#undef QCOMP

    if (z < 2) {
        bf16* out = (z == 0) ? qb : kb;
#pragma unroll
        for (int nt = 0; nt < 4; nt++) {
            int col = n0 + wc * 64 + nt * 16 + l15;
            float bc = bias[col];
#pragma unroll
            for (int mt = 0; mt < 4; mt++) {
                int rowb = m0 + wr * 64 + mt * 16 + quad * 4;
#pragma unroll
                for (int r = 0; r < 4; r++) {
                    float v = (acc[mt][nt][r] + bc) * scale;
                    out[(size_t)(rowb + r) * HID + col] = (bf16)v;
                }
            }
        }
    } else {
        // V: bias, transpose through LDS (st[col][row], stride 136), store to
        // vt[b][h][s] coalesced. Rows m0..m0+127 are keys s of batch b.
        bf16* st = (bf16*)sm;   // [128][136] = 34816 B, dbuf no longer needed
#pragma unroll
        for (int nt = 0; nt < 4; nt++) {
            int colL = wc * 64 + nt * 16 + l15;
            float bc = bias[n0 + colL];
#pragma unroll
            for (int mt = 0; mt < 4; mt++) {
                int rowL = wr * 64 + mt * 16 + quad * 4;
#pragma unroll
                for (int r = 0; r < 4; r++)
                    st[(size_t)colL * 136 + rowL + r] = (bf16)(acc[mt][nt][r] + bc);
            }
        }
        __syncthreads();
        int b  = m0 >> 11;          // batch
        int s0 = m0 & 2047;         // seq offset
        bf16* vbase = vt + ((size_t)b * HID + n0) * SEQ + s0;
#pragma unroll
        for (int i = 0; i < 8; i++) {
            int p = i * 256 + t;    // 2048 chunks of 16 B
            int colL = p >> 4, ch = p & 15;
            *(uint4*)((char*)vbase + (size_t)colL * SEQ * 2 + ch * 16) =
                *(const uint4*)&st[(size_t)colL * 136 + ch * 8];
        }
    }
}

// ---------------------------------------------------------------------------
// kernel 4: flash attention. R8: replace __syncthreads (which drains vmcnt(0)
// on the just-issued STAGE DMA -> full L2-feed stall every tile at 1 block/CU)
// with raw s_barrier + repositioned vmcnt wait (T3/T4): the vmcnt(0) at the
// top of a tile only drains loads issued a FULL TILE earlier; the prefetch
// for tile t+1 is issued right after the data-ready barrier and stays in
// flight across both barriers of tile t. setprio(1) wraps MFMA clusters (T5).
//
// Hazard ledger (2 barriers/tile):
//   BAR_A (post-vmcnt(0)): buf-cur DMA visible to all; all PV(t-1) reads of
//     buf(t-1) and P retired (they feed MFMAs executed pre-barrier) -> safe
//     for STAGE(t+1) to overwrite buf(t-1) and QKP(t) to overwrite P.
//   BAR_B (post-lgkmcnt(0)): P ds_writes visible before PV's P reads.
// ---------------------------------------------------------------------------
__global__ __launch_bounds__(512, 2) void
k_attn(const bf16* __restrict__ qb, const bf16* __restrict__ kbuf,
       const bf16* __restrict__ vt, float* __restrict__ out) {
    __shared__ __align__(16) char smem[136832];
    char* sm = smem;
    // bytes: [0,65536) K dbuf  [65536,131072) V dbuf
    //        [131072,136192) P [64][80B]  [136192,136704) l exchange

    int j = blockIdx.x;
    int b = j & 7, qblk = j >> 3;
    int t = threadIdx.x, w = t >> 6, lane = t & 63, quad = lane >> 4, l15 = lane & 15;
    int rg = w & 3, kg = w >> 2;

    const bf16* Qrow   = qb + ((size_t)b * SEQ + qblk * 64 + rg * 16) * HID;
    const bf16* Kbase  = kbuf + (size_t)b * SEQ * HID;
    const bf16* VTbase = vt + (size_t)b * HID * SEQ;

    const char* kE = sm + (kg * 16 + l15) * 1024 + ((quad ^ (l15 & 7)) * 16);
    const char* kO = sm + (kg * 16 + l15) * 1024 + (((4 + quad) ^ (l15 & 7)) * 16);
    char*       pW = sm + 131072 + (rg * 16 + quad * 4) * 80 + (kg * 16 + l15) * 2;
    const char* pR = sm + 131072 + l15 * 80 + quad * 16;
    const char* vA = sm + 65536 + w * 4096 + l15 * 64 + ((quad ^ (l15 & 3)) * 16);
    float*      mlx = (float*)(sm + 136192);   // [2 kg][64 rows]

    const char* kgp = (const char*)Kbase + w * 1024 + ((lane ^ w) * 16);
    const char* vgp = (const char*)VTbase + (w * 16 + (lane >> 2)) * 4096
                      + (((lane & 3) ^ ((lane >> 2) & 3)) * 16);

    bf16x8 qf[16];
#pragma unroll
    for (int kt = 0; kt < 16; kt++)
        qf[kt] = *(const bf16x8*)&Qrow[(size_t)l15 * HID + kt * 32 + quad * 8];

    float l_acc[4] = {0.f, 0.f, 0.f, 0.f};
    f32x4 o_acc[16] = {};

    const int NIT = SEQ / 32;   // 64

#define STAGE(S)                                                              \
    {                                                                         \
        _Pragma("unroll")                                                     \
        for (int jj = 0; jj < 4; jj++)                                        \
            gl2lds16(kgp + jj * 8192,                                         \
                     sm + (S) * 32768 + jj * 8192 + w * 1024);                \
        _Pragma("unroll")                                                     \
        for (int jj = 0; jj < 4; jj++)                                        \
            gl2lds16(vgp + jj * 524288,                                       \
                     sm + 65536 + (S) * 32768 + jj * 8192 + w * 1024);        \
        kgp += 32768; vgp += 64;                                              \
    }

#define QKP(CUR)                                                              \
    {                                                                         \
        f32x4 sa = {}, sb = {};                                               \
        __builtin_amdgcn_s_setprio(1);                                        \
        _Pragma("unroll")                                                     \
        for (int kt = 0; kt < 16; kt += 2) {                                  \
            bf16x8 kfe = *(const bf16x8*)(kE + (kt >> 1) * 128 + (CUR) * 32768); \
            bf16x8 kfo = *(const bf16x8*)(kO + (kt >> 1) * 128 + (CUR) * 32768); \
            sa = MFMA16(qf[kt], kfe, sa);                                     \
            sb = MFMA16(qf[kt + 1], kfo, sb);                                 \
        }                                                                     \
        __builtin_amdgcn_s_setprio(0);                                        \
        _Pragma("unroll")                                                     \
        for (int r = 0; r < 4; r++) {                                         \
            float p = __expf(sa[r] + sb[r] - 8.0f);                           \
            l_acc[r] += p;                                                    \
            *(bf16*)(pW + r * 80) = (bf16)p;                                  \
        }                                                                     \
    }

#define PV(CUR)                                                               \
    {                                                                         \
        bf16x8 pa0 = *(const bf16x8*)(pR + 0 * 1280);                         \
        bf16x8 pa1 = *(const bf16x8*)(pR + 1 * 1280);                         \
        bf16x8 pa2 = *(const bf16x8*)(pR + 2 * 1280);                         \
        bf16x8 pa3 = *(const bf16x8*)(pR + 3 * 1280);                         \
        __builtin_amdgcn_s_setprio(1);                                        \
        _Pragma("unroll")                                                     \
        for (int hs = 0; hs < 4; hs++) {                                      \
            bf16x8 vf = *(const bf16x8*)(vA + hs * 1024 + (CUR) * 32768);     \
            o_acc[0 * 4 + hs] = MFMA16(pa0, vf, o_acc[0 * 4 + hs]);           \
            o_acc[1 * 4 + hs] = MFMA16(pa1, vf, o_acc[1 * 4 + hs]);           \
            o_acc[2 * 4 + hs] = MFMA16(pa2, vf, o_acc[2 * 4 + hs]);           \
            o_acc[3 * 4 + hs] = MFMA16(pa3, vf, o_acc[3 * 4 + hs]);           \
        }                                                                     \
        __builtin_amdgcn_s_setprio(0);                                        \
    }

// data-ready barrier: drains ONLY the loads for buf-cur (issued a full tile
// ago); the prefetch for the next buffer is issued AFTER this barrier.
#define BAR_A()                                                               \
    {                                                                         \
        asm volatile("s_waitcnt vmcnt(0)" ::: "memory");                      \
        __builtin_amdgcn_sched_barrier(0);                                    \
        __builtin_amdgcn_s_barrier();                                         \
        __builtin_amdgcn_sched_barrier(0);                                    \
    }

// P-exchange barrier: LDS writes visible, no vmcnt drain (prefetch in flight)
#define BAR_B()                                                               \
    {                                                                         \
        asm volatile("s_waitcnt lgkmcnt(0)" ::: "memory");                    \
        __builtin_amdgcn_sched_barrier(0);                                    \
        __builtin_amdgcn_s_barrier();                                         \
        __builtin_amdgcn_sched_barrier(0);                                    \
    }

    STAGE(0);

    for (int ii = 0; ii < NIT / 2; ii++) {
        // ---- tile 2*ii   (buf 0)
        BAR_A();
        STAGE(1);
        __builtin_amdgcn_sched_barrier(0);
        QKP(0);
        BAR_B();
        PV(0);
        // ---- tile 2*ii+1 (buf 1)
        BAR_A();
        if (ii < NIT / 2 - 1) STAGE(0);
        __builtin_amdgcn_sched_barrier(0);
        QKP(1);
        BAR_B();
        PV(1);
    }

    float lw[4];
#pragma unroll
    for (int r = 0; r < 4; r++) {
        float v = l_acc[r];
        for (int d = 1; d < 16; d <<= 1) v += __shfl_xor(v, d, 64);
        lw[r] = v;
    }
    __syncthreads();   // all waves past the loop before mlx writes
    if (l15 == 0)
#pragma unroll
        for (int r = 0; r < 4; r++) mlx[kg * 64 + rg * 16 + quad * 4 + r] = lw[r];
    __syncthreads();

    float lt[4][4];
#pragma unroll
    for (int rgp = 0; rgp < 4; rgp++)
#pragma unroll
        for (int r = 0; r < 4; r++) {
            int row = rgp * 16 + quad * 4 + r;
            lt[rgp][r] = 1.0f / (mlx[row] + mlx[64 + row]);
        }
    float* obase = out + ((size_t)b * SEQ + qblk * 64) * HID + w * 64;
#pragma unroll
    for (int rgp = 0; rgp < 4; rgp++)
#pragma unroll
        for (int hs = 0; hs < 4; hs++)
#pragma unroll
            for (int r = 0; r < 4; r++)
                obase[(size_t)(rgp * 16 + quad * 4 + r) * HID + hs * 16 + l15] =
                    o_acc[rgp * 4 + hs][r] * lt[rgp][r];
#undef STAGE
#undef QKP
#undef PV
#undef BAR_A
#undef BAR_B
}

// ---------------------------------------------------------------------------
extern "C" void kernel_launch(void* const* d_in, const int* in_sizes, int n_in,
                              void* d_out, int out_size, void* d_ws, size_t ws_size,
                              hipStream_t stream) {
    const float* x  = (const float*)d_in[0];
    const float* Wq = (const float*)d_in[1];
    const float* bq = (const float*)d_in[2];
    const float* Wk = (const float*)d_in[3];
    const float* bk = (const float*)d_in[4];
    const float* Wv = (const float*)d_in[5];
    const float* bv = (const float*)d_in[6];
    float* out = (float*)d_out;

    char* ws = (char*)d_ws;
    const size_t SZ_XB = (size_t)MTOT * HID * 2;        // 16 MiB
    const size_t SZ_WT = (size_t)HID * HID * 2;         // 512 KiB each
    bf16* xb = (bf16*)(ws);
    bf16* wt = (bf16*)(ws + SZ_XB);
    bf16* qb = (bf16*)(ws + SZ_XB + 3 * SZ_WT);
    bf16* kb = (bf16*)(ws + SZ_XB + 3 * SZ_WT + SZ_XB);
    bf16* vt = (bf16*)(ws + SZ_XB + 3 * SZ_WT + 2 * SZ_XB);

    k_convert_x<<<2048, 256, 0, stream>>>(x, xb, MTOT * HID / 4);
    k_transpose_w<<<dim3(16, 16, 3), 256, 0, stream>>>(Wq, Wk, Wv, wt);
    k_qkv<<<dim3(4, 128, 3), 256, 0, stream>>>(xb, wt, bq, bk, bv, qb, kb, vt);
    k_attn<<<256, 512, 0, stream>>>(qb, kb, vt, out);
}